// Round 22
// baseline (5821.821 us; speedup 1.0000x reference)
//
#include <hip/hip_runtime.h>

// DownSampling: B=16, N=16384, C=128, M=4096. f32 in/out.
// LOCKED ORACLE SEMANTICS (R14, absmax==0): per point,
//   dx=px-cx; dy=py-cy; dz=pz-cz;
//   d = fma(dz,dz, fma(dx,dx, rn(dy*dy)))   [XLA-GPU tree contraction]
//   dist = min(dist, d); argmax = (max value, MIN index).
// R22 = R19 (best, 5047us) + PACKED distance phase: float2 ext_vector ops
// lower to v_pk_{add,mul,fma}_f32 (VOP3P, full rate on gfx950: same 2-cyc
// issue as scalar, 2 f32/lane) with per-half IEEE RN == scalar ops bitwise.
// No inline asm, no register pins (R15/R16's failure causes). Per point-pair
// 9 insts vs 15 -> -48 insts/wave/iter on an issue-bound kernel.
// Tail (reduce/atomic/barriers/LDS cache) = R19 verbatim.
#define B_   16
#define N_   16384
#define C_   128
#define M_   4096
#define TPB  1024
#define PPT  16    // points per thread
#define NPAIR 8    // PPT/2 float2 pairs
#define NC   10880 // points with coords cached in LDS (3*NC*4 = 130560 B)

typedef float v2f __attribute__((ext_vector_type(2)));

#define DPP_QUAD_XOR1   0xB1   // quad_perm [1,0,3,2]
#define DPP_QUAD_XOR2   0x4E   // quad_perm [2,3,0,1]
#define DPP_HALF_MIRROR 0x141  // mirror within 8-lane half-rows
#define DPP_ROW_MIRROR  0x140  // mirror within 16-lane rows
#define SWZ_XOR16       0x401F // BitMode xor-16 within 32-lane groups

// value-only max join via DPP (VALU pipe) — R19-proven
#define VMAX_DPP(V, CTRL) do{                                                      \
    float _o = __int_as_float(__builtin_amdgcn_mov_dpp(__float_as_int(V),          \
                                                       (CTRL), 0xF, 0xF, 0));      \
    (V) = fmaxf((V), _o);                                                          \
}while(0)

// value-only max join via ds_swizzle xor pattern — R19-proven
#define VMAX_SWZ(V, PAT) do{                                                       \
    float _o = __int_as_float(__builtin_amdgcn_ds_swizzle(__float_as_int(V), PAT));\
    (V) = fmaxf((V), _o);                                                          \
}while(0)

__global__ __launch_bounds__(TPB, 4) void fps_kernel(const float* __restrict__ xyz,
                                                     int* __restrict__ idx_out)
{
    const int b = blockIdx.x;
    const int t = threadIdx.x;
    const int wid  = t >> 6;
    const int lane = t & 63;
    const float* xb = xyz + (size_t)b * 3 * N_;

    extern __shared__ float smem[];          // dynamic: coord cache
    float* cX = smem;
    float* cY = smem + NC;
    float* cZ = smem + 2 * NC;

    v2f px[NPAIR], py[NPAIR], pz[NPAIR], dd[NPAIR];

    // Load 16 consecutive points per thread (float4-vectorized, coalesced),
    // repacked as float2 pairs (register aliasing, no extra ops).
    {
        const float4* x4 = reinterpret_cast<const float4*>(xb);
        const float4* y4 = reinterpret_cast<const float4*>(xb + N_);
        const float4* z4 = reinterpret_cast<const float4*>(xb + 2 * N_);
        #pragma unroll
        for (int q = 0; q < 4; ++q) {
            float4 vx = x4[t * 4 + q];
            float4 vy = y4[t * 4 + q];
            float4 vz = z4[t * 4 + q];
            px[q*2+0] = (v2f){vx.x, vx.y}; px[q*2+1] = (v2f){vx.z, vx.w};
            py[q*2+0] = (v2f){vy.x, vy.y}; py[q*2+1] = (v2f){vy.z, vy.w};
            pz[q*2+0] = (v2f){vz.x, vz.y}; pz[q*2+1] = (v2f){vz.z, vz.w};
        }
    }
    #pragma unroll
    for (int p = 0; p < NPAIR; ++p) dd[p] = (v2f){1e10f, 1e10f};  // BIG sentinel

    // Fill LDS coord cache (one-time; visible by first use via iter-1 barriers).
    for (int p = t; p < NC; p += TPB) {
        cX[p] = xb[p];
        cY[p] = xb[N_ + p];
        cZ[p] = xb[2 * N_ + p];
    }

    __shared__ float lv[4][16];   // per-wave value partials (4-ring)
    __shared__ int   widx[4];     // winning-index word per ring

    if (t < 4) widx[t] = 0x7fffffff;   // init rings; visible after B1(m=1)

    if (t == 0) idx_out[b * M_ + 0] = 0;   // deterministic start at index 0

    // First centroid = point 0.
    float cx = xb[0], cy = xb[N_], cz = xb[2 * N_];

    for (int m = 1; m < M_; ++m) {
        const int buf = m & 3;

        // ---- a: PACKED distance update (locked semantics, v_pk_* RN per half)
        const v2f cxx = (v2f){cx, cx};
        const v2f cyy = (v2f){cy, cy};
        const v2f czz = (v2f){cz, cz};
        float vmax = -1.0f;
        #pragma unroll
        for (int p = 0; p < NPAIR; ++p) {
            v2f dx = px[p] - cxx;                       // v_pk_add_f32 (neg)
            v2f dy = py[p] - cyy;
            v2f dz = pz[p] - czz;
            v2f q  = __builtin_elementwise_fma(dz, dz,  // v_pk_fma_f32
                        __builtin_elementwise_fma(dx, dx, dy * dy));
            float n0 = fminf(dd[p][0], q[0]);
            float n1 = fminf(dd[p][1], q[1]);
            dd[p][0] = n0;
            dd[p][1] = n1;
            vmax = fmaxf(fmaxf(vmax, n0), n1);          // v_max3_f32 (exact)
        }
        const float lmax = vmax;   // pre-reduce local max for match test

        // ---- b: wave value-reduce (4 DPP + xor16 swizzle + xor32 shfl) [R19]
        VMAX_DPP(vmax, DPP_QUAD_XOR1);
        VMAX_DPP(vmax, DPP_QUAD_XOR2);
        VMAX_DPP(vmax, DPP_HALF_MIRROR);
        VMAX_DPP(vmax, DPP_ROW_MIRROR);
        VMAX_SWZ(vmax, SWZ_XOR16);
        vmax = fmaxf(vmax, __shfl_xor(vmax, 32));

        // ---- c: publish wave partial; reset ring for iter m+2 (barrier-safe)
        if (lane == 0) lv[buf][wid] = vmax;
        if (t == 0) widx[(m + 2) & 3] = 0x7fffffff;
        __syncthreads();   // B1

        // ---- d: block value-reduce (16 partials, pure DPP within 16-lane row)
        float v2 = (lane < 16) ? lv[buf][lane] : -1.0f;
        VMAX_DPP(v2, DPP_QUAD_XOR1);
        VMAX_DPP(v2, DPP_QUAD_XOR2);
        VMAX_DPP(v2, DPP_HALF_MIRROR);
        VMAX_DPP(v2, DPP_ROW_MIRROR);
        const float bmax = __int_as_float(
            __builtin_amdgcn_readfirstlane(__float_as_int(v2)));

        // ---- e: rare index-find (only matching thread(s); waves skip via execz)
        if (lmax == bmax) {
            int cand = 0;
            #pragma unroll
            for (int i = PPT - 1; i >= 0; --i)      // descending: smallest slot wins
                cand = (dd[i >> 1][i & 1] == bmax) ? i : cand;
            atomicMin(&widx[buf], t * PPT + cand);  // global MIN index (tie-break)
        }
        __syncthreads();   // B2

        // ---- f: read winner, emit, reload centroid (LDS-cached or VMEM)
        const int j = __builtin_amdgcn_readfirstlane(widx[buf]);
        if (t == 0) idx_out[b * M_ + m] = j;
        if (j < NC) {   // uniform scalar branch; ds_read broadcast (~70cyc)
            cx = cX[j];
            cy = cY[j];
            cz = cZ[j];
        } else {        // fallback: L2 loads (~200cyc), 34% of iterations
            cx = xb[j];
            cy = xb[N_ + j];
            cz = xb[2 * N_ + j];
        }
    }
}

// -------------------------------------------------------------------------
// Gather kernel: one block per (batch, output row). Rows 0..2 = xyz, 3..130 =
// feature channels. Raw f32 passthrough of gathered values.
// -------------------------------------------------------------------------
__global__ void gather_kernel(const float* __restrict__ xyz,
                              const float* __restrict__ feat,
                              const int*   __restrict__ idx,
                              float*       __restrict__ out)
{
    const int blk = blockIdx.x;
    const int b = blk / (3 + C_);
    const int r = blk % (3 + C_);
    const int* idb = idx + b * M_;

    if (r < 3) {
        const float* src = xyz + ((size_t)b * 3 + r) * N_;
        float*       dst = out + ((size_t)b * 3 + r) * M_;
        for (int m = threadIdx.x; m < M_; m += blockDim.x)
            dst[m] = src[idb[m]];
    } else {
        const int c = r - 3;
        const float* src = feat + ((size_t)b * C_ + c) * N_;
        float*       dst = out + (size_t)B_ * 3 * M_ + ((size_t)b * C_ + c) * M_;
        for (int m = threadIdx.x; m < M_; m += blockDim.x)
            dst[m] = src[idb[m]];
    }
}

extern "C" void kernel_launch(void* const* d_in, const int* in_sizes, int n_in,
                              void* d_out, int out_size, void* d_ws, size_t ws_size,
                              hipStream_t stream)
{
    const float* xyz  = (const float*)d_in[0];   // [16, 3, 16384] f32
    const float* feat = (const float*)d_in[1];   // [16, 128, 16384] f32
    float* out = (float*)d_out;                  // [16*3*4096] + [16*128*4096] f32
    int*   idx = (int*)d_ws;                     // [16, 4096] int32 scratch

    const size_t dyn_lds = (size_t)3 * NC * sizeof(float);   // 130560 B
    fps_kernel<<<dim3(B_), dim3(TPB), dyn_lds, stream>>>(xyz, idx);
    gather_kernel<<<dim3(B_ * (3 + C_)), dim3(256), 0, stream>>>(xyz, feat, idx, out);
}